// Round 10
// baseline (120.333 us; speedup 1.0000x reference)
//
#include <hip/hip_runtime.h>
#include <math.h>

// Problem constants
#define NTOK 16384
#define DDIM 4096
#define NEXP 64
#define KTOP 4

// GEMM config: block = 64 tokens x all 64 experts x FULL K (no split-K).
#define BK   128               // floats of k per stage
#define NSTG (DDIM / BK)       // 32 stages
#define TPB  64                // tokens per block
#define NBLK (NTOK / TPB)      // 256 blocks

typedef __attribute__((ext_vector_type(8))) short short8;
typedef __attribute__((ext_vector_type(4))) float f32x4;

// ws layout: Whi [NEXP][DDIM] ushort (512 KB) ; Wlo same (512 KB)

__device__ __forceinline__ unsigned short f2bf_rtn(float x) {
    unsigned int b = __float_as_uint(x);
    return (unsigned short)((b + 0x7FFFu + ((b >> 16) & 1u)) >> 16);
}
__device__ __forceinline__ float bf2f(unsigned short h) {
    return __uint_as_float(((unsigned int)h) << 16);
}
__device__ __forceinline__ short8 mk8(unsigned int a, unsigned int b,
                                      unsigned int c, unsigned int d) {
    union { unsigned int u[4]; short8 s; } p;
    p.u[0] = a; p.u[1] = b; p.u[2] = c; p.u[3] = d;
    return p.s;
}
__device__ __forceinline__ void gl2lds16(const void* g, void* l) {
    __builtin_amdgcn_global_load_lds(
        (const __attribute__((address_space(1))) unsigned int*)g,
        (__attribute__((address_space(3))) unsigned int*)l, 16, 0, 0);
}

// ---------------- Kernel 1: split W into bf16 hi/lo, zero counts -------------
__global__ __launch_bounds__(256) void prep_kernel(
    const float* __restrict__ W, unsigned short* __restrict__ Whi,
    unsigned short* __restrict__ Wlo, float* __restrict__ counts)
{
    int idx = blockIdx.x * 256 + threadIdx.x;   // 0 .. 64*4096
    float x = W[idx];
    unsigned short h = f2bf_rtn(x);
    float lo = x - bf2f(h);
    Whi[idx] = h;
    Wlo[idx] = f2bf_rtn(lo);
    if (blockIdx.x == 0 && threadIdx.x < NEXP) counts[threadIdx.x] = 0.0f;
}

// ---------------- Kernel 2: fused GEMM (bf16x3 MFMA) + routing ---------------
// 256 blocks x 512 threads (8 waves, 2x4 wave grid), 1 block/CU, LDS ~145 KB.
// Each block sweeps a CONTIGUOUS 512-KB X span (64 rows x 16 KB): per stage a
// row's 512 B is delivered by ONE wave-instruction (page-friendly sequential
// DRAM bursts). gload_lds double-buffered, one barrier per stage. Epilogue:
// logits -> LDS -> in-block softmax + group-limited top-k (no part buffer).
__global__ __launch_bounds__(512, 2) void gate_kernel(
    const float* __restrict__ X, const unsigned short* __restrict__ Whi,
    const unsigned short* __restrict__ Wlo, float* __restrict__ outW,
    float* __restrict__ outI, float* __restrict__ counts)
{
    __shared__ float          sX[2][TPB * BK];    // 2 x 32 KB
    __shared__ unsigned short sH[2][NEXP * BK];   // 2 x 16 KB
    __shared__ unsigned short sL[2][NEXP * BK];   // 2 x 16 KB
    __shared__ float          lgt[TPB][66];       // 16.9 KB logits
    __shared__ int            hist[NEXP];

    const int tid  = threadIdx.x;
    const int lane = tid & 63;
    const int w    = tid >> 6;                 // wave 0..7
    const int wm   = w >> 2;                   // token half 0..1
    const int wn   = w & 3;                    // expert quarter 0..3
    const int tok0 = blockIdx.x * TPB;

    if (tid < NEXP) hist[tid] = 0;

    // ---- X staging geometry: instr (w,i): seg = w*4+i covers LDS floats
    // [seg*256,+256) = rows {seg*2, seg*2+1}; lane l -> row seg*2+(l>>5),
    // chunk pc = l&31 (4-float chunks). Source chunk = pc ^ (row&15)
    // (16-B-granularity XOR swizzle; involution, applied source-side).
    const float* xsrc[4];
    int xdstf[4];
    #pragma unroll
    for (int i = 0; i < 4; ++i) {
        const int seg = w * 4 + i;
        const int r0  = seg * 2 + (lane >> 5);
        const int pc  = lane & 31;
        xsrc[i]  = X + (size_t)(tok0 + r0) * DDIM + ((pc ^ (r0 & 15)) * 4);
        xdstf[i] = seg * 256;
    }
    // ---- W staging: instr (w,j): seg2 = w*2+j covers LDS shorts [seg2*512,+512)
    // = expert rows {seg2*4..+3}; lane l -> e = seg2*4+(l>>4), chunk sc = l&15
    // (8-short chunks). Source chunk = sc ^ (e&15).
    const unsigned short *whsrc[2], *wlsrc[2];
    int wdsts[2];
    #pragma unroll
    for (int j = 0; j < 2; ++j) {
        const int seg2 = w * 2 + j;
        const int e    = seg2 * 4 + (lane >> 4);
        const int sc   = lane & 15;
        const size_t o = (size_t)e * DDIM + ((sc ^ (e & 15)) * 8);
        whsrc[j] = Whi + o;
        wlsrc[j] = Wlo + o;
        wdsts[j] = seg2 * 512;
    }

    // ---- prologue: stage 0 into buffer 0 ----
    #pragma unroll
    for (int i = 0; i < 4; ++i) gl2lds16(xsrc[i], &sX[0][xdstf[i]]);
    #pragma unroll
    for (int j = 0; j < 2; ++j) {
        gl2lds16(whsrc[j], &sH[0][wdsts[j]]);
        gl2lds16(wlsrc[j], &sL[0][wdsts[j]]);
    }
    __syncthreads();

    // ---- fragment geometry ----
    const int fr = lane & 15;                  // token row / expert col in frag
    const int fg = lane >> 4;                  // k subgroup 0..3
    const int rowA0 = (wm * 32 + fr) * BK;     // float base of row, mg=0
    const int rowA1 = rowA0 + 16 * BK;         // mg=1
    const int eB    = (wn * 16 + fr) * BK;     // short base of expert row

    f32x4 acc[2];
    acc[0] = (f32x4){0.f, 0.f, 0.f, 0.f};
    acc[1] = (f32x4){0.f, 0.f, 0.f, 0.f};

    for (int st = 0; st < NSTG; ++st) {
        const float*          cx = sX[st & 1];
        const unsigned short* ch = sH[st & 1];
        const unsigned short* cl = sL[st & 1];

        // ---- issue next stage's loads ----
        if (st + 1 < NSTG) {
            const int nb = (st + 1) & 1;
            const int ko = (st + 1) * BK;
            #pragma unroll
            for (int i = 0; i < 4; ++i)
                gl2lds16(xsrc[i] + ko, &sX[nb][xdstf[i]]);
            #pragma unroll
            for (int j = 0; j < 2; ++j) {
                gl2lds16(whsrc[j] + ko, &sH[nb][wdsts[j]]);
                gl2lds16(wlsrc[j] + ko, &sL[nb][wdsts[j]]);
            }
        }

        // ---- 4 k-steps of 32: reads + convert + 6 MFMAs each ----
        #pragma unroll
        for (int ks = 0; ks < 4; ++ks) {
            const int ch0 = ks * 8 + fg * 2;   // 4-float chunk of A frag
            const float4 a00 = *(const float4*)&cx[rowA0 + ((ch0     ) ^ fr) * 4];
            const float4 a01 = *(const float4*)&cx[rowA0 + ((ch0 + 1) ^ fr) * 4];
            const float4 a10 = *(const float4*)&cx[rowA1 + ((ch0     ) ^ fr) * 4];
            const float4 a11 = *(const float4*)&cx[rowA1 + ((ch0 + 1) ^ fr) * 4];

            short8 ahi[2], alo[2];
            #pragma unroll
            for (int mg = 0; mg < 2; ++mg) {
                const float4 qa = mg ? a10 : a00;
                const float4 qb = mg ? a11 : a01;
                const unsigned int u0 = __float_as_uint(qa.x), u1 = __float_as_uint(qa.y);
                const unsigned int u2 = __float_as_uint(qa.z), u3 = __float_as_uint(qa.w);
                const unsigned int u4 = __float_as_uint(qb.x), u5 = __float_as_uint(qb.y);
                const unsigned int u6 = __float_as_uint(qb.z), u7 = __float_as_uint(qb.w);
                unsigned int hi0 = (u0 >> 16) | (u1 & 0xFFFF0000u);
                unsigned int hi1 = (u2 >> 16) | (u3 & 0xFFFF0000u);
                unsigned int hi2 = (u4 >> 16) | (u5 & 0xFFFF0000u);
                unsigned int hi3 = (u6 >> 16) | (u7 & 0xFFFF0000u);
                const float l0 = qa.x - __uint_as_float(u0 & 0xFFFF0000u);
                const float l1 = qa.y - __uint_as_float(u1 & 0xFFFF0000u);
                const float l2 = qa.z - __uint_as_float(u2 & 0xFFFF0000u);
                const float l3 = qa.w - __uint_as_float(u3 & 0xFFFF0000u);
                const float l4 = qb.x - __uint_as_float(u4 & 0xFFFF0000u);
                const float l5 = qb.y - __uint_as_float(u5 & 0xFFFF0000u);
                const float l6 = qb.z - __uint_as_float(u6 & 0xFFFF0000u);
                const float l7 = qb.w - __uint_as_float(u7 & 0xFFFF0000u);
                unsigned int lo0 = (__float_as_uint(l0) >> 16) | (__float_as_uint(l1) & 0xFFFF0000u);
                unsigned int lo1 = (__float_as_uint(l2) >> 16) | (__float_as_uint(l3) & 0xFFFF0000u);
                unsigned int lo2 = (__float_as_uint(l4) >> 16) | (__float_as_uint(l5) & 0xFFFF0000u);
                unsigned int lo3 = (__float_as_uint(l6) >> 16) | (__float_as_uint(l7) & 0xFFFF0000u);
                ahi[mg] = mk8(hi0, hi1, hi2, hi3);
                alo[mg] = mk8(lo0, lo1, lo2, lo3);
            }

            const int cb = (ks * 4 + fg) ^ fr; // 8-short chunk of B frag
            const short8 bh = *(const short8*)&ch[eB + cb * 8];
            const short8 bl = *(const short8*)&cl[eB + cb * 8];

            #pragma unroll
            for (int mg = 0; mg < 2; ++mg) {
                acc[mg] = __builtin_amdgcn_mfma_f32_16x16x32_bf16(ahi[mg], bh, acc[mg], 0, 0, 0);
                acc[mg] = __builtin_amdgcn_mfma_f32_16x16x32_bf16(ahi[mg], bl, acc[mg], 0, 0, 0);
                acc[mg] = __builtin_amdgcn_mfma_f32_16x16x32_bf16(alo[mg], bh, acc[mg], 0, 0, 0);
            }
        }

        __syncthreads();   // drains vmcnt: next buffer ready, LDS safe to reuse
    }

    // ---- epilogue: logits to LDS ----
    // C/D: col = fr (expert within wn*16), row = fg*4 + r (token within mg*16)
    #pragma unroll
    for (int mg = 0; mg < 2; ++mg)
        #pragma unroll
        for (int r = 0; r < 4; ++r)
            lgt[wm * 32 + mg * 16 + fg * 4 + r][wn * 16 + fr] = acc[mg][r];
    __syncthreads();

    // ---- routing: wave w handles tokens tok0 + w*8 .. +7 ----
    for (int t = 0; t < 8; ++t) {
        const int nl = w * 8 + t;
        const int n  = tok0 + nl;
        const float L = lgt[nl][lane];

        // softmax over 64 experts (wave = expert axis)
        float m = L;
        #pragma unroll
        for (int off = 32; off > 0; off >>= 1) m = fmaxf(m, __shfl_xor(m, off));
        float p = expf(L - m);
        float ssum = p;
        #pragma unroll
        for (int off = 32; off > 0; off >>= 1) ssum += __shfl_xor(ssum, off);
        const float score = p / ssum;

        // group max within each 8-lane group
        float gm = score;
        gm = fmaxf(gm, __shfl_xor(gm, 1));
        gm = fmaxf(gm, __shfl_xor(gm, 2));
        gm = fmaxf(gm, __shfl_xor(gm, 4));

        // top-4 groups (ties -> lower index)
        float ga[8];
        #pragma unroll
        for (int g = 0; g < 8; ++g) ga[g] = __shfl(gm, g * 8);
        unsigned selmask = 0u;
        #pragma unroll
        for (int r = 0; r < 4; ++r) {
            float best = -INFINITY; int bg = 0;
            #pragma unroll
            for (int g = 0; g < 8; ++g) {
                bool taken  = (selmask >> g) & 1u;
                bool better = (!taken) && (ga[g] > best);
                bg   = better ? g : bg;
                best = better ? ga[g] : best;
            }
            selmask |= (1u << bg);
        }

        // mask non-selected groups, wave-wide top-4 (ties -> lower idx)
        float ms = ((selmask >> (lane >> 3)) & 1u) ? score : -INFINITY;
        float wk[4]; int wi[4];
        #pragma unroll
        for (int r = 0; r < 4; ++r) {
            float v = ms; int ix = lane;
            #pragma unroll
            for (int off = 32; off > 0; off >>= 1) {
                float vo = __shfl_xor(v, off);
                int   io = __shfl_xor(ix, off);
                if (vo > v || (vo == v && io < ix)) { v = vo; ix = io; }
            }
            wk[r] = v; wi[r] = ix;
            if (lane == ix) ms = -INFINITY;
        }

        if (lane == 0) {
            *(float4*)&outW[(size_t)n * 4] = make_float4(wk[0], wk[1], wk[2], wk[3]);
            *(float4*)&outI[(size_t)n * 4] =
                make_float4((float)wi[0], (float)wi[1], (float)wi[2], (float)wi[3]);
            atomicAdd(&hist[wi[0]], 1);
            atomicAdd(&hist[wi[1]], 1);
            atomicAdd(&hist[wi[2]], 1);
            atomicAdd(&hist[wi[3]], 1);
        }
    }

    __syncthreads();
    if (tid < NEXP) atomicAdd(&counts[tid], (float)hist[tid]);
}

extern "C" void kernel_launch(void* const* d_in, const int* in_sizes, int n_in,
                              void* d_out, int out_size, void* d_ws, size_t ws_size,
                              hipStream_t stream) {
    const float* X = (const float*)d_in[0];
    const float* W = (const float*)d_in[1];

    float* outW   = (float*)d_out;                    // [N,4] weights
    float* outI   = outW + (size_t)NTOK * KTOP;       // [N,4] indices (as float)
    float* counts = outW + (size_t)2 * NTOK * KTOP;   // [64]  counts  (as float)

    unsigned short* Whi = (unsigned short*)d_ws;               // 512 KB
    unsigned short* Wlo = Whi + (size_t)NEXP * DDIM;           // 512 KB

    prep_kernel<<<(NEXP * DDIM) / 256, 256, 0, stream>>>(W, Whi, Wlo, counts);
    gate_kernel<<<NBLK, 512, 0, stream>>>(X, Whi, Wlo, outW, outI, counts);
}